// Round 10
// baseline (378.826 us; speedup 1.0000x reference)
//
#include <hip/hip_runtime.h>
#include <hip/hip_bf16.h>

#define B_    32
#define CIN   64
#define HW    56
#define COUT  128
#define M_    256
#define P_    576
#define L_    3136
#define N_    100352

typedef __hip_bfloat16 bf16;
typedef unsigned short u16;
typedef __attribute__((ext_vector_type(2))) unsigned short u16x2;
typedef __attribute__((ext_vector_type(8))) short bf16x8;
typedef __attribute__((ext_vector_type(8))) unsigned short u16x8;
typedef __attribute__((ext_vector_type(4))) float f32x4;

__device__ __forceinline__ float bits2f(u16 u){ return __uint_as_float(((unsigned)u) << 16); }
__device__ __forceinline__ u16 f2bf(float f){
  bf16 h = __float2bfloat16(f);
  return *(u16*)&h;
}
__device__ __forceinline__ void gload16(const void* g, void* l){
  __builtin_amdgcn_global_load_lds((const __attribute__((address_space(1))) void*)g,
                                   (__attribute__((address_space(3))) void*)l, 16, 0, 0);
}

// ---- K0: build fragment-major operand layouts + b2 -------------------------
__global__ __launch_bounds__(256) void k0_prep(const float* __restrict__ C,
                                               const float* __restrict__ W,
                                               u16* __restrict__ CbP, u16* __restrict__ CtP,
                                               float* __restrict__ b2v, u16* __restrict__ WbP){
  __shared__ float red[4];
  const int t = threadIdx.x;
  const int bid = blockIdx.x;
  if (bid < M_){
    const int m = bid;
    float s = 0.f;
    for (int p = t; p < P_; p += 256){
      float vr = bits2f(f2bf(C[(size_t)m*P_ + p]));
      s += vr*vr;
    }
    #pragma unroll
    for (int off = 32; off >= 1; off >>= 1) s += __shfl_xor(s, off);
    if ((t & 63) == 0) red[t >> 6] = s;
    __syncthreads();
    if (t == 0) b2v[m] = red[0] + red[1] + red[2] + red[3];
  } else if (bid < M_ + 72){
    const int u = (bid - M_)*256 + t;          // [0, 18432)
    const int f = u >> 6, lane = u & 63;
    const int g = lane >> 4, lr = lane & 15;
    const int k = f % 18, fj = f / 18;
    const int j = fj & 3, wvq = fj >> 2;
    const int m = wvq*64 + j*16 + lr;
    const int p = k*32 + g*8;
    u16x8 o;
    #pragma unroll
    for (int c = 0; c < 8; ++c) o[c] = f2bf(C[(size_t)m*P_ + p + c]);
    *(u16x8*)&CbP[(size_t)u*8] = o;
  } else if (bid < M_ + 144){
    const int u = (bid - M_ - 72)*256 + t;     // [0, 18432)
    const int f = u >> 6, lane = u & 63;
    const int g = lane >> 4, lr = lane & 15;
    const int mc = f & 7, fj = f >> 3;
    const int j = fj % 9, q = fj / 9;
    const int p = q*144 + j*16 + lr;
    const int m = mc*32 + g*8;
    u16x8 o;
    #pragma unroll
    for (int c = 0; c < 8; ++c) o[c] = f2bf(C[(size_t)(m + c)*P_ + p]);
    *(u16x8*)&CtP[(size_t)u*8] = o;
  } else {
    const int u = (bid - M_ - 144)*256 + t;    // [0, 9216)
    const int f = u >> 6, lane = u & 63;
    const int g = lane >> 4, lr = lane & 15;
    const int k = f % 18, fi = f / 18;
    const int i = fi & 3, wn = fi >> 2;
    const int co = wn*64 + i*16 + lr;
    const int q = k*32 + g*8;
    u16x8 o;
    #pragma unroll
    for (int c = 0; c < 8; ++c) o[c] = f2bf(W[(size_t)co*P_ + q + c]);
    *(u16x8*)&WbP[(size_t)u*8] = o;
  }
}

// ---- K1 (fallback): unfold -> standard A + a2 ------------------------------
__global__ __launch_bounds__(256) void k1_unfold(const float* __restrict__ x,
                                                 u16* __restrict__ A,
                                                 float* __restrict__ a2v){
  __shared__ float xt[64*175 + 1];
  const int t = threadIdx.x;
  const int bid = blockIdx.x;
  const int b = bid / HW, h = bid % HW;

  for (int idx = t; idx < 64*174; idx += 256){
    const int c = idx / 174, rem = idx - c*174;
    const int r = rem / 58, wc = rem - r*58;
    const int iy = h + r - 1, ix = wc - 1;
    float v = 0.f;
    if ((unsigned)iy < (unsigned)HW && (unsigned)ix < (unsigned)HW)
      v = x[((size_t)b*CIN + c)*L_ + iy*HW + ix];
    xt[c*175 + r*58 + wc] = v;
  }
  __syncthreads();

  const int n0 = b*L_ + h*56;
  u16* Arow = A + (size_t)n0 * P_;
  #pragma unroll
  for (int k = 0; k < 2; ++k){
    const int pb = k*512 + t*2;
    if (pb < P_){
      const int c0 = pb/9,     rr0 = pb - c0*9;
      const int c1 = (pb+1)/9, rr1 = (pb+1) - c1*9;
      const float* s0 = &xt[c0*175 + (rr0/3)*58 + (rr0 - (rr0/3)*3)];
      const float* s1 = &xt[c1*175 + (rr1/3)*58 + (rr1 - (rr1/3)*3)];
      for (int w = 0; w < 56; ++w){
        u16x2 o = { f2bf(s0[w]), f2bf(s1[w]) };
        *(u16x2*)&Arow[(size_t)w*P_ + pb] = o;
      }
    }
  }

  const int wid = t >> 6, lane = t & 63;
  for (int w = wid; w < 56; w += 4){
    const float* src = &xt[lane*175 + w];
    float s = 0.f;
    #pragma unroll
    for (int r = 0; r < 3; ++r)
      #pragma unroll
      for (int dj = 0; dj < 3; ++dj){
        float vr = bits2f(f2bf(src[r*58 + dj]));
        s += vr*vr;
      }
    #pragma unroll
    for (int off = 32; off >= 1; off >>= 1) s += __shfl_xor(s, off);
    if (lane == 0) a2v[n0 + w] = s;
  }
}

// ---- K1B (AP path): unfold -> frag-major AP + a2. Block = 64 patches. ------
// AP unit u = (k*4+i)*64 + (g*16+lr) holds A[l0+i*16+lr][k*32+g*8 .. +8].
__global__ __launch_bounds__(256) void k1b_unfold_ap(const float* __restrict__ x,
                                                     u16* __restrict__ AP,
                                                     float* __restrict__ a2v){
  __shared__ float xt[64*233 + 1];   // 64 ch x (4 rows x 58 cols), stride 233
  const int t = threadIdx.x;
  const int blk = blockIdx.x;
  const int n0 = blk * 64;
  const int b  = n0 / L_;
  const int l0 = n0 - b * L_;        // L_ = 49*64 -> block within one batch
  const int h0 = l0 / 56;

  for (int idx = t; idx < 64*232; idx += 256){
    const int c = idx / 232, rem = idx - c*232;
    const int ry = rem / 58, wc = rem - ry*58;
    const int iy = h0 - 1 + ry, ix = wc - 1;
    float v = 0.f;
    if ((unsigned)iy < (unsigned)HW && (unsigned)ix < (unsigned)HW)
      v = x[((size_t)b*CIN + c)*L_ + iy*HW + ix];
    xt[c*233 + ry*58 + wc] = v;
  }
  __syncthreads();

  u16* APb = AP + (size_t)blk * 36864;   // 4608 units x 8 u16
  #pragma unroll
  for (int e = 0; e < 18; ++e){
    const int u = t + e*256;
    const int lane_u = u & 63, fi = u >> 6;
    const int i = fi & 3, k = fi >> 2;
    const int lr = lane_u & 15, g = lane_u >> 4;
    const int l = l0 + i*16 + lr;
    const int h = l / 56, w = l - h*56;
    const int ryb = h - h0;              // 0 or 1
    u16x8 o;
    #pragma unroll
    for (int c2 = 0; c2 < 8; ++c2){
      const int p = k*32 + g*8 + c2;
      const int ch = p / 9, rr = p - ch*9;
      const int di = rr / 3, dj = rr - di*3;
      o[c2] = f2bf(xt[ch*233 + (ryb + di)*58 + w + dj]);
    }
    *(u16x8*)&APb[(size_t)u*8] = o;
  }

  const int wid = t >> 6, lane = t & 63;
  for (int lo = wid; lo < 64; lo += 4){
    const int l = l0 + lo;
    const int h = l / 56, w = l - h*56;
    const float* src = &xt[lane*233 + (h - h0)*58 + w];
    float s = 0.f;
    #pragma unroll
    for (int r = 0; r < 3; ++r)
      #pragma unroll
      for (int dj = 0; dj < 3; ++dj){
        float vr = bits2f(f2bf(src[r*58 + dj]));
        s += vr*vr;
      }
    #pragma unroll
    for (int off = 32; off >= 1; off >>= 1) s += __shfl_xor(s, off);
    if (lane == 0) a2v[n0 + lo] = s;
  }
}

// ---- K23: fused assign+transform. Block = 64 rows n. -----------------------
// USE_AP=0: P1 via LDS ring from standard A (round-8 structure); av from A; F in place.
// USE_AP=1: P1 barrier-free from frag-major AP; av from AP; F to separate buffer.
template<int USE_AP>
__global__ __launch_bounds__(256, 2) void k23_fused(const u16* __restrict__ Abuf,
    const u16* __restrict__ CbP, const u16* __restrict__ CtP,
    const float* __restrict__ a2v, const float* __restrict__ b2v,
    const float* __restrict__ temp_p, u16* __restrict__ Fout){
  __shared__ __align__(16) char lds[71680];
  u16*   Sl  = (u16*)lds;             // 64 x 264 u16 = 33792 B (persistent)
  char*  R2  = lds + 33792;           // 37888 B region
  short* AlB = (short*)R2;            // 3 bufs x 64x32 shorts (P1, fallback only)
  float* red = (float*)R2;            // 256 f (softmax)
  u16*   Fl  = (u16*)R2;              // 64 x 296 u16 = 37888 B (F staging)

  const int t = threadIdx.x;
  const int lane = t & 63;
  const int wv = t >> 6;
  const int g  = lane >> 4;
  const int lr = lane & 15;
  const int n0 = blockIdx.x * 64;
  const int sw = (g ^ (lr & 3)) << 3;
  const float temp = *temp_p;
  const u16* APb = Abuf + (size_t)blockIdx.x * 36864;  // AP path only

  // ================= phase 1: G = A * Cb^T =================
  f32x4 acc[4][4];
  #pragma unroll
  for (int i = 0; i < 4; ++i)
    #pragma unroll
    for (int j = 0; j < 4; ++j) acc[i][j] = (f32x4){0.f,0.f,0.f,0.f};

  if constexpr (USE_AP){
    #pragma unroll
    for (int k = 0; k < 18; ++k){
      bf16x8 af[4], bb[4];
      #pragma unroll
      for (int i = 0; i < 4; ++i)
        af[i] = *(const bf16x8*)(APb + ((size_t)(k*4 + i)*64 + lane)*8);
      #pragma unroll
      for (int j = 0; j < 4; ++j)
        bb[j] = *(const bf16x8*)(CbP + (((size_t)(wv*4 + j)*18 + k)*64 + lane)*8);
      #pragma unroll
      for (int i = 0; i < 4; ++i)
        #pragma unroll
        for (int j = 0; j < 4; ++j)
          acc[i][j] = __builtin_amdgcn_mfma_f32_16x16x32_bf16(af[i], bb[j], acc[i][j], 0, 0, 0);
    }
  } else {
    const int arow = t >> 2, ach = t & 3;
    const int agch = ach ^ (arow & 3);
    const u16* Asrc = Abuf + (size_t)(n0 + arow)*P_ + agch*8;
    gload16(Asrc +  0, &AlB[0*2048 + t*8]);
    gload16(Asrc + 32, &AlB[1*2048 + t*8]);
    bf16x8 bbc[4], bbn[4];
    #pragma unroll
    for (int j = 0; j < 4; ++j)
      bbc[j] = *(const bf16x8*)(CbP + (((size_t)(wv*4 + j)*18 + 0)*64 + lane)*8);

    #pragma unroll
    for (int k = 0; k < 18; ++k){
      if (k + 2 < 18) gload16(Asrc + (k+2)*32, &AlB[((k+2)%3)*2048 + t*8]);
      if (k < 16)      asm volatile("s_waitcnt vmcnt(2)" ::: "memory");
      else if (k==16)  asm volatile("s_waitcnt vmcnt(1)" ::: "memory");
      else             asm volatile("s_waitcnt vmcnt(0)" ::: "memory");
      __builtin_amdgcn_s_barrier();
      __builtin_amdgcn_sched_barrier(0);
      const short* Alc = &AlB[(k%3)*2048];
      bf16x8 af[4];
      #pragma unroll
      for (int i = 0; i < 4; ++i)
        af[i] = *(const bf16x8*)&Alc[(i*16 + lr)*32 + sw];
      if (k + 1 < 18){
        #pragma unroll
        for (int j = 0; j < 4; ++j)
          bbn[j] = *(const bf16x8*)(CbP + (((size_t)(wv*4 + j)*18 + (k+1))*64 + lane)*8);
      }
      #pragma unroll
      for (int i = 0; i < 4; ++i)
        #pragma unroll
        for (int j = 0; j < 4; ++j)
          acc[i][j] = __builtin_amdgcn_mfma_f32_16x16x32_bf16(af[i], bbc[j], acc[i][j], 0, 0, 0);
      __builtin_amdgcn_s_barrier();
      __builtin_amdgcn_sched_barrier(0);
      if (k + 1 < 18){
        #pragma unroll
        for (int j = 0; j < 4; ++j) bbc[j] = bbn[j];
      }
    }
  }

  // ---- softmax over all 256 m ----
  float a2r[4][4], b2r[4];
  #pragma unroll
  for (int i = 0; i < 4; ++i)
    #pragma unroll
    for (int r = 0; r < 4; ++r) a2r[i][r] = a2v[n0 + i*16 + g*4 + r];
  #pragma unroll
  for (int j = 0; j < 4; ++j) b2r[j] = b2v[wv*64 + j*16 + lr];

  float rmax[4][4];
  #pragma unroll
  for (int i = 0; i < 4; ++i)
    #pragma unroll
    for (int r = 0; r < 4; ++r) rmax[i][r] = -3.4e38f;

  #pragma unroll
  for (int i = 0; i < 4; ++i)
    #pragma unroll
    for (int j = 0; j < 4; ++j)
      #pragma unroll
      for (int r = 0; r < 4; ++r){
        float d2 = fmaxf(a2r[i][r] + b2r[j] - 2.f*acc[i][j][r], 1e-12f);
        float lg = -temp * sqrtf(d2);
        acc[i][j][r] = lg;
        rmax[i][r] = fmaxf(rmax[i][r], lg);
      }
  #pragma unroll
  for (int i = 0; i < 4; ++i)
    #pragma unroll
    for (int r = 0; r < 4; ++r){
      float v = rmax[i][r];
      v = fmaxf(v, __shfl_xor(v, 1));
      v = fmaxf(v, __shfl_xor(v, 2));
      v = fmaxf(v, __shfl_xor(v, 4));
      v = fmaxf(v, __shfl_xor(v, 8));
      rmax[i][r] = v;
    }
  __syncthreads();
  if (lr == 0){
    #pragma unroll
    for (int i = 0; i < 4; ++i)
      #pragma unroll
      for (int r = 0; r < 4; ++r) red[wv*64 + i*16 + g*4 + r] = rmax[i][r];
  }
  __syncthreads();
  #pragma unroll
  for (int i = 0; i < 4; ++i)
    #pragma unroll
    for (int r = 0; r < 4; ++r){
      const int row = i*16 + g*4 + r;
      rmax[i][r] = fmaxf(fmaxf(red[row], red[64+row]), fmaxf(red[128+row], red[192+row]));
    }
  float rsum[4][4];
  #pragma unroll
  for (int i = 0; i < 4; ++i)
    #pragma unroll
    for (int r = 0; r < 4; ++r) rsum[i][r] = 0.f;
  #pragma unroll
  for (int i = 0; i < 4; ++i)
    #pragma unroll
    for (int j = 0; j < 4; ++j)
      #pragma unroll
      for (int r = 0; r < 4; ++r){
        float pe = __expf(acc[i][j][r] - rmax[i][r]);
        acc[i][j][r] = pe;
        rsum[i][r] += pe;
      }
  #pragma unroll
  for (int i = 0; i < 4; ++i)
    #pragma unroll
    for (int r = 0; r < 4; ++r){
      float v = rsum[i][r];
      v += __shfl_xor(v, 1);
      v += __shfl_xor(v, 2);
      v += __shfl_xor(v, 4);
      v += __shfl_xor(v, 8);
      rsum[i][r] = v;
    }
  __syncthreads();
  if (lr == 0){
    #pragma unroll
    for (int i = 0; i < 4; ++i)
      #pragma unroll
      for (int r = 0; r < 4; ++r) red[wv*64 + i*16 + g*4 + r] = rsum[i][r];
  }
  __syncthreads();
  #pragma unroll
  for (int i = 0; i < 4; ++i)
    #pragma unroll
    for (int r = 0; r < 4; ++r){
      const int row = i*16 + g*4 + r;
      const float invr = 1.f / (red[row] + red[64+row] + red[128+row] + red[192+row]);
      #pragma unroll
      for (int j = 0; j < 4; ++j)
        Sl[(size_t)row*264 + wv*64 + j*16 + lr] = f2bf(acc[i][j][r] * invr);
    }
  __syncthreads();                 // Sl visible; R2 free

  // ========== phase 2: T = Sl * Ct (no barriers, batch frag loads) ==========
  f32x4 acc2[4][9];
  #pragma unroll
  for (int i = 0; i < 4; ++i)
    #pragma unroll
    for (int j = 0; j < 9; ++j) acc2[i][j] = (f32x4){0.f,0.f,0.f,0.f};

  for (int mc = 0; mc < 8; ++mc){
    bf16x8 af2[4], bb2[9];
    #pragma unroll
    for (int i = 0; i < 4; ++i)
      af2[i] = *(const bf16x8*)&Sl[(size_t)(i*16 + lr)*264 + mc*32 + g*8];
    #pragma unroll
    for (int j = 0; j < 9; ++j)
      bb2[j] = *(const bf16x8*)(CtP + (((size_t)(wv*9 + j)*8 + mc)*64 + lane)*8);
    #pragma unroll
    for (int j = 0; j < 9; ++j)
      #pragma unroll
      for (int i = 0; i < 4; ++i)
        acc2[i][j] = __builtin_amdgcn_mfma_f32_16x16x32_bf16(af2[i], bb2[j], acc2[i][j], 0, 0, 0);
  }

  // ---- F write: two 288-p halves, skip-RMW coalesced ----------------------
  const float inv = 1.f / (temp + 1.f);
  const float tscale = temp * inv;
  #pragma unroll
  for (int h = 0; h < 2; ++h){
    __syncthreads();
    if ((wv >> 1) == h){
      const int pbase = (wv & 1) * 144;
      #pragma unroll
      for (int i = 0; i < 4; ++i)
        #pragma unroll
        for (int j = 0; j < 9; ++j)
          #pragma unroll
          for (int r = 0; r < 4; ++r)
            Fl[(i*16 + g*4 + r)*296 + pbase + j*16 + lr] = f2bf(acc2[i][j][r] * tscale);
    }
    __syncthreads();
    #pragma unroll
    for (int e = 0; e < 9; ++e){
      const int v = t + e*256;
      const int row = v / 36, col = (v - row*36) * 8;
      u16x8 tv = *(const u16x8*)&Fl[row*296 + col];
      u16x8 av;
      if constexpr (USE_AP){
        const int p0 = h*288 + col;
        const int kk = p0 >> 5, gg = (p0 >> 3) & 3;
        const int ii = row >> 4, lrr = row & 15;
        av = *(const u16x8*)(APb + ((size_t)((kk*4 + ii)*64 + gg*16 + lrr))*8);
      } else {
        av = *(const u16x8*)(Fout + (size_t)(n0 + row)*P_ + h*288 + col);
      }
      u16x8 o;
      #pragma unroll
      for (int e2 = 0; e2 < 8; ++e2)
        o[e2] = f2bf(bits2f(tv[e2]) + bits2f(av[e2]) * inv);
      *(u16x8*)(Fout + (size_t)(n0 + row)*P_ + h*288 + col) = o;
    }
  }
}

// ---- K4: MFMA GEMM out = WbP * F (+bias), mask fused into F staging --------
__global__ __launch_bounds__(256) void k4_conv(const u16* __restrict__ F,
    const u16* __restrict__ WbP, const float* __restrict__ bias,
    float* __restrict__ out){
  __shared__ short Fl[128*40];
  const int t = threadIdx.x;
  const int lane = t & 63;
  const int w = t >> 6;
  const int wn = w >> 1;
  const int ws = w & 1;
  const int g  = lane >> 4;
  const int lr = lane & 15;
  const int b  = blockIdx.y;
  const int s0 = blockIdx.x * 128;
  const u16* Fb = F + (size_t)b * ((size_t)P_ * L_);

  f32x4 acc[4][4];
  #pragma unroll
  for (int i = 0; i < 4; ++i)
    #pragma unroll
    for (int j = 0; j < 4; ++j) acc[i][j] = (f32x4){0.f,0.f,0.f,0.f};

  for (int step = 0; step < 18; ++step){
    const int q0 = step * 32;
    __syncthreads();
    #pragma unroll
    for (int e = 0; e < 2; ++e){
      const int c = t + e*256;
      const int ql = c & 31, sch = c >> 5;
      const int q  = q0 + ql;
      const int sbase = s0 + sch*8;
      const int scl = (sbase < L_ - 8) ? sbase : (L_ - 8);
      u16x8 v = *(const u16x8*)(Fb + (size_t)q*L_ + scl);
      const int q3 = q/3;
      const bool kx0 = (q - q3*3) == 0;
      const bool ky0 = (q3 % 3) == 0;
      const int r0 = sbase % 56;
      #pragma unroll
      for (int u = 0; u < 8; ++u){
        const bool m0 = ky0 && (sbase + u) < 56;
        const bool m1 = kx0 && ((r0 + u) == 0 || (r0 + u) == 56);
        Fl[(sch*8 + u)*40 + ql] = (m0 || m1) ? (short)0 : (short)v[u];
      }
    }
    __syncthreads();
    bf16x8 af[4], bb[4];
    #pragma unroll
    for (int i = 0; i < 4; ++i)
      af[i] = *(const bf16x8*)(WbP + (((size_t)(wn*4 + i)*18 + step)*64 + lane)*8);
    #pragma unroll
    for (int j = 0; j < 4; ++j)
      bb[j] = *(const bf16x8*)&Fl[(ws*64 + j*16 + lr)*40 + g*8];
    #pragma unroll
    for (int i = 0; i < 4; ++i)
      #pragma unroll
      for (int j = 0; j < 4; ++j)
        acc[i][j] = __builtin_amdgcn_mfma_f32_16x16x32_bf16(af[i], bb[j], acc[i][j], 0, 0, 0);
  }

  #pragma unroll
  for (int i = 0; i < 4; ++i)
    #pragma unroll
    for (int r = 0; r < 4; ++r){
      const int co = wn*64 + i*16 + g*4 + r;
      const float bv = bias[co];
      #pragma unroll
      for (int j = 0; j < 4; ++j){
        const int s = s0 + ws*64 + j*16 + lr;
        if (s < L_) out[((size_t)b*COUT + co)*L_ + s] = acc[i][j][r] + bv;
      }
    }
}

extern "C" void kernel_launch(void* const* d_in, const int* in_sizes, int n_in,
                              void* d_out, int out_size, void* d_ws, size_t ws_size,
                              hipStream_t stream){
  const float* x      = (const float*)d_in[0];
  const float* weight = (const float*)d_in[1];
  const float* bias   = (const float*)d_in[2];
  const float* cc     = (const float*)d_in[3];
  const float* temp_p = (const float*)d_in[4];
  float* out = (float*)d_out;

  char* ws = (char*)d_ws;
  const size_t NEED_AP = 232350720ULL;

  if (ws_size >= NEED_AP){
    u16*   AP  = (u16*)(ws);                 // 115,605,504 B (frag-major A)
    u16*   F   = (u16*)(ws + 115605504);     // 115,605,504 B (standard F)
    float* a2v = (float*)(ws + 231211008);   //     401,408 B
    float* b2v = (float*)(ws + 231612416);   //       1,024 B
    u16*   CbP = (u16*)(ws + 231613440);     //     294,912 B
    u16*   CtP = (u16*)(ws + 231908352);     //     294,912 B
    u16*   WbP = (u16*)(ws + 232203264);     //     147,456 B

    k0_prep       <<<436,          256, 0, stream>>>(cc, weight, CbP, CtP, b2v, WbP);
    k1b_unfold_ap <<<N_/64,        256, 0, stream>>>(x, AP, a2v);
    k23_fused<1>  <<<N_/64,        256, 0, stream>>>(AP, CbP, CtP, a2v, b2v, temp_p, F);
    k4_conv       <<<dim3(25, B_), 256, 0, stream>>>(F, WbP, bias, out);
  } else {
    u16*   A   = (u16*)(ws);                 // 115,605,504 B (standard A / F in place)
    float* a2v = (float*)(ws + 166985728);
    float* b2v = (float*)(ws + 167387136);
    u16*   CbP = (u16*)(ws + 167388160);
    u16*   CtP = (u16*)(ws + 167683072);
    u16*   WbP = (u16*)(ws + 167977984);

    k0_prep     <<<436,          256, 0, stream>>>(cc, weight, CbP, CtP, b2v, WbP);
    k1_unfold   <<<B_*HW,        256, 0, stream>>>(x, A, a2v);
    k23_fused<0><<<N_/64,        256, 0, stream>>>(A, CbP, CtP, a2v, b2v, temp_p, A);
    k4_conv     <<<dim3(25, B_), 256, 0, stream>>>(A, WbP, bias, out);
  }
}

// Round 11
// 301.964 us; speedup vs baseline: 1.2545x; 1.2545x over previous
//
#include <hip/hip_runtime.h>
#include <hip/hip_bf16.h>

#define B_    32
#define CIN   64
#define HW    56
#define COUT  128
#define M_    256
#define P_    576
#define L_    3136
#define N_    100352

typedef __hip_bfloat16 bf16;
typedef unsigned short u16;
typedef __attribute__((ext_vector_type(2))) unsigned short u16x2;
typedef __attribute__((ext_vector_type(8))) short bf16x8;
typedef __attribute__((ext_vector_type(8))) unsigned short u16x8;
typedef __attribute__((ext_vector_type(4))) float f32x4;

__device__ __forceinline__ float bits2f(u16 u){ return __uint_as_float(((unsigned)u) << 16); }
__device__ __forceinline__ u16 f2bf(float f){
  bf16 h = __float2bfloat16(f);
  return *(u16*)&h;
}
__device__ __forceinline__ void gload16(const void* g, void* l){
  __builtin_amdgcn_global_load_lds((const __attribute__((address_space(1))) void*)g,
                                   (__attribute__((address_space(3))) void*)l, 16, 0, 0);
}

// ---- K0: build fragment-major operand layouts + b2 -------------------------
__global__ __launch_bounds__(256) void k0_prep(const float* __restrict__ C,
                                               const float* __restrict__ W,
                                               u16* __restrict__ CbP, u16* __restrict__ CtP,
                                               float* __restrict__ b2v, u16* __restrict__ WbP){
  __shared__ float red[4];
  const int t = threadIdx.x;
  const int bid = blockIdx.x;
  if (bid < M_){
    const int m = bid;
    float s = 0.f;
    for (int p = t; p < P_; p += 256){
      float vr = bits2f(f2bf(C[(size_t)m*P_ + p]));
      s += vr*vr;
    }
    #pragma unroll
    for (int off = 32; off >= 1; off >>= 1) s += __shfl_xor(s, off);
    if ((t & 63) == 0) red[t >> 6] = s;
    __syncthreads();
    if (t == 0) b2v[m] = red[0] + red[1] + red[2] + red[3];
  } else if (bid < M_ + 72){
    const int u = (bid - M_)*256 + t;          // [0, 18432)
    const int f = u >> 6, lane = u & 63;
    const int g = lane >> 4, lr = lane & 15;
    const int k = f % 18, fj = f / 18;
    const int j = fj & 3, wvq = fj >> 2;
    const int m = wvq*64 + j*16 + lr;
    const int p = k*32 + g*8;
    u16x8 o;
    #pragma unroll
    for (int c = 0; c < 8; ++c) o[c] = f2bf(C[(size_t)m*P_ + p + c]);
    *(u16x8*)&CbP[(size_t)u*8] = o;
  } else if (bid < M_ + 144){
    const int u = (bid - M_ - 72)*256 + t;     // [0, 18432)
    const int f = u >> 6, lane = u & 63;
    const int g = lane >> 4, lr = lane & 15;
    const int mc = f & 7, fj = f >> 3;
    const int j = fj % 9, q = fj / 9;
    const int p = q*144 + j*16 + lr;
    const int m = mc*32 + g*8;
    u16x8 o;
    #pragma unroll
    for (int c = 0; c < 8; ++c) o[c] = f2bf(C[(size_t)(m + c)*P_ + p]);
    *(u16x8*)&CtP[(size_t)u*8] = o;
  } else {
    const int u = (bid - M_ - 144)*256 + t;    // [0, 9216)
    const int f = u >> 6, lane = u & 63;
    const int g = lane >> 4, lr = lane & 15;
    const int k = f % 18, fi = f / 18;
    const int i = fi & 3, wn = fi >> 2;
    const int co = wn*64 + i*16 + lr;
    const int q = k*32 + g*8;
    u16x8 o;
    #pragma unroll
    for (int c = 0; c < 8; ++c) o[c] = f2bf(W[(size_t)co*P_ + q + c]);
    *(u16x8*)&WbP[(size_t)u*8] = o;
  }
}

// ---- K1 (fallback): unfold -> standard A + a2 ------------------------------
__global__ __launch_bounds__(256) void k1_unfold(const float* __restrict__ x,
                                                 u16* __restrict__ A,
                                                 float* __restrict__ a2v){
  __shared__ float xt[64*175 + 1];
  const int t = threadIdx.x;
  const int bid = blockIdx.x;
  const int b = bid / HW, h = bid % HW;

  for (int idx = t; idx < 64*174; idx += 256){
    const int c = idx / 174, rem = idx - c*174;
    const int r = rem / 58, wc = rem - r*58;
    const int iy = h + r - 1, ix = wc - 1;
    float v = 0.f;
    if ((unsigned)iy < (unsigned)HW && (unsigned)ix < (unsigned)HW)
      v = x[((size_t)b*CIN + c)*L_ + iy*HW + ix];
    xt[c*175 + r*58 + wc] = v;
  }
  __syncthreads();

  const int n0 = b*L_ + h*56;
  u16* Arow = A + (size_t)n0 * P_;
  #pragma unroll
  for (int k = 0; k < 2; ++k){
    const int pb = k*512 + t*2;
    if (pb < P_){
      const int c0 = pb/9,     rr0 = pb - c0*9;
      const int c1 = (pb+1)/9, rr1 = (pb+1) - c1*9;
      const float* s0 = &xt[c0*175 + (rr0/3)*58 + (rr0 - (rr0/3)*3)];
      const float* s1 = &xt[c1*175 + (rr1/3)*58 + (rr1 - (rr1/3)*3)];
      for (int w = 0; w < 56; ++w){
        u16x2 o = { f2bf(s0[w]), f2bf(s1[w]) };
        *(u16x2*)&Arow[(size_t)w*P_ + pb] = o;
      }
    }
  }

  const int wid = t >> 6, lane = t & 63;
  for (int w = wid; w < 56; w += 4){
    const float* src = &xt[lane*175 + w];
    float s = 0.f;
    #pragma unroll
    for (int r = 0; r < 3; ++r)
      #pragma unroll
      for (int dj = 0; dj < 3; ++dj){
        float vr = bits2f(f2bf(src[r*58 + dj]));
        s += vr*vr;
      }
    #pragma unroll
    for (int off = 32; off >= 1; off >>= 1) s += __shfl_xor(s, off);
    if (lane == 0) a2v[n0 + w] = s;
  }
}

// ---- K1B (AP path, v2): unfold -> frag-major AP + a2. Block = 64 patches. --
// Unit u = (e*4+wv)*64 + lane holds A[l0+wv*16+lr][e*32+g*8 .. +8].
// xt staged as bf16 (rounded once); gather uses incremental (ch,di,dj) walk.
__global__ __launch_bounds__(256) void k1b_unfold_ap(const float* __restrict__ x,
                                                     u16* __restrict__ AP,
                                                     float* __restrict__ a2v){
  __shared__ __align__(16) u16 xt[64*264];   // 64 ch x (4 rows x 64 cols), 33,792 B
  const int t = threadIdx.x;
  const int blk = blockIdx.x;
  const int n0 = blk * 64;
  const int b  = n0 / L_;
  const int l0 = n0 - b * L_;                // 64-aligned within batch
  const int h0 = l0 / 56;

  // ---- stage x window as bf16: wave-uniform (c,ry), lane = col. ----
  const float* xb = x + (size_t)b * CIN * L_;
  const int wc = t & 63;
  const int ix = wc - 1;
  #pragma unroll 4
  for (int iter = 0; iter < 64; ++iter){
    const int cw = (t >> 6) + iter*4;        // 0..255, wave-uniform
    const int c  = cw & 63;
    const int ry = cw >> 6;                  // 0..3
    const int iy = h0 - 1 + ry;
    float v = 0.f;
    if ((unsigned)iy < 56u && (unsigned)ix < 56u)
      v = xb[(size_t)c*L_ + iy*56 + ix];
    xt[c*264 + ry*64 + wc] = f2bf(v);
  }
  __syncthreads();

  // ---- AP fragments + fused a2 ----
  const int lane = t & 63;
  const int wv = t >> 6;
  const int g  = lane >> 4;
  const int lr = lane & 15;
  const int l  = l0 + wv*16 + lr;
  const int h  = l / 56, w = l - h*56;
  const int hbw = (h - h0)*64 + w;           // per-thread constant base

  const int p0 = g*8;
  int rr  = p0 - ((p0 >= 9) + (p0 >= 18))*9; // p0 % 9
  int chB = ((p0 >= 9) + (p0 >= 18))*264;    // (p0/9)*264
  u16* APb = AP + (size_t)blk * 36864 + (size_t)(wv*64 + lane)*8;
  float s2 = 0.f;

  #pragma unroll
  for (int e = 0; e < 18; ++e){
    const int di = (rr >= 3) + (rr >= 6);
    int dj = rr - di*3;
    int addr = chB + hbw + di*64 + dj;
    int rr2 = rr;
    u16x8 o;
    #pragma unroll
    for (int c2 = 0; c2 < 8; ++c2){
      const u16 val = xt[addr];
      o[c2] = val;
      const float vr = bits2f(val);
      s2 = fmaf(vr, vr, s2);
      const bool w9 = (rr2 == 8);
      const bool w3 = (dj == 2);
      addr += w9 ? 134 : (w3 ? 62 : 1);      // +1 | row-jump | ch-jump
      dj   = w3 ? 0 : dj + 1;
      rr2  = w9 ? 0 : rr2 + 1;
    }
    *(u16x8*)(APb + (size_t)e*2048) = o;
    const bool uw = (rr + 5 >= 9);           // p += 32: rr += 5 mod 9, ch += 3/4
    rr  = rr + 5 - (uw ? 9 : 0);
    chB += uw ? 1056 : 792;
  }

  // a2: reduce over the 4 g-lanes (lane bits 4,5)
  s2 += __shfl_xor(s2, 16);
  s2 += __shfl_xor(s2, 32);
  if (g == 0) a2v[n0 + wv*16 + lr] = s2;
}

// ---- K23: fused assign+transform. Block = 64 rows n. -----------------------
// USE_AP=0: P1 via LDS ring from standard A; av from A; F in place.
// USE_AP=1: P1 barrier-free from frag-major AP; av from AP; F to separate buffer.
template<int USE_AP>
__global__ __launch_bounds__(256, 2) void k23_fused(const u16* __restrict__ Abuf,
    const u16* __restrict__ CbP, const u16* __restrict__ CtP,
    const float* __restrict__ a2v, const float* __restrict__ b2v,
    const float* __restrict__ temp_p, u16* __restrict__ Fout){
  __shared__ __align__(16) char lds[71680];
  u16*   Sl  = (u16*)lds;             // 64 x 264 u16 = 33792 B (persistent)
  char*  R2  = lds + 33792;           // 37888 B region
  short* AlB = (short*)R2;            // 3 bufs x 64x32 shorts (P1, fallback only)
  float* red = (float*)R2;            // 256 f (softmax)
  u16*   Fl  = (u16*)R2;              // 64 x 296 u16 = 37888 B (F staging)

  const int t = threadIdx.x;
  const int lane = t & 63;
  const int wv = t >> 6;
  const int g  = lane >> 4;
  const int lr = lane & 15;
  const int n0 = blockIdx.x * 64;
  const int sw = (g ^ (lr & 3)) << 3;
  const float temp = *temp_p;
  const u16* APb = Abuf + (size_t)blockIdx.x * 36864;  // AP path only

  // ================= phase 1: G = A * Cb^T =================
  f32x4 acc[4][4];
  #pragma unroll
  for (int i = 0; i < 4; ++i)
    #pragma unroll
    for (int j = 0; j < 4; ++j) acc[i][j] = (f32x4){0.f,0.f,0.f,0.f};

  if constexpr (USE_AP){
    #pragma unroll
    for (int k = 0; k < 18; ++k){
      bf16x8 af[4], bb[4];
      #pragma unroll
      for (int i = 0; i < 4; ++i)
        af[i] = *(const bf16x8*)(APb + ((size_t)(k*4 + i)*64 + lane)*8);
      #pragma unroll
      for (int j = 0; j < 4; ++j)
        bb[j] = *(const bf16x8*)(CbP + (((size_t)(wv*4 + j)*18 + k)*64 + lane)*8);
      #pragma unroll
      for (int i = 0; i < 4; ++i)
        #pragma unroll
        for (int j = 0; j < 4; ++j)
          acc[i][j] = __builtin_amdgcn_mfma_f32_16x16x32_bf16(af[i], bb[j], acc[i][j], 0, 0, 0);
    }
  } else {
    const int arow = t >> 2, ach = t & 3;
    const int agch = ach ^ (arow & 3);
    const u16* Asrc = Abuf + (size_t)(n0 + arow)*P_ + agch*8;
    gload16(Asrc +  0, &AlB[0*2048 + t*8]);
    gload16(Asrc + 32, &AlB[1*2048 + t*8]);
    bf16x8 bbc[4], bbn[4];
    #pragma unroll
    for (int j = 0; j < 4; ++j)
      bbc[j] = *(const bf16x8*)(CbP + (((size_t)(wv*4 + j)*18 + 0)*64 + lane)*8);

    #pragma unroll
    for (int k = 0; k < 18; ++k){
      if (k + 2 < 18) gload16(Asrc + (k+2)*32, &AlB[((k+2)%3)*2048 + t*8]);
      if (k < 16)      asm volatile("s_waitcnt vmcnt(2)" ::: "memory");
      else if (k==16)  asm volatile("s_waitcnt vmcnt(1)" ::: "memory");
      else             asm volatile("s_waitcnt vmcnt(0)" ::: "memory");
      __builtin_amdgcn_s_barrier();
      __builtin_amdgcn_sched_barrier(0);
      const short* Alc = &AlB[(k%3)*2048];
      bf16x8 af[4];
      #pragma unroll
      for (int i = 0; i < 4; ++i)
        af[i] = *(const bf16x8*)&Alc[(i*16 + lr)*32 + sw];
      if (k + 1 < 18){
        #pragma unroll
        for (int j = 0; j < 4; ++j)
          bbn[j] = *(const bf16x8*)(CbP + (((size_t)(wv*4 + j)*18 + (k+1))*64 + lane)*8);
      }
      #pragma unroll
      for (int i = 0; i < 4; ++i)
        #pragma unroll
        for (int j = 0; j < 4; ++j)
          acc[i][j] = __builtin_amdgcn_mfma_f32_16x16x32_bf16(af[i], bbc[j], acc[i][j], 0, 0, 0);
      __builtin_amdgcn_s_barrier();
      __builtin_amdgcn_sched_barrier(0);
      if (k + 1 < 18){
        #pragma unroll
        for (int j = 0; j < 4; ++j) bbc[j] = bbn[j];
      }
    }
  }

  // ---- softmax over all 256 m ----
  float a2r[4][4], b2r[4];
  #pragma unroll
  for (int i = 0; i < 4; ++i)
    #pragma unroll
    for (int r = 0; r < 4; ++r) a2r[i][r] = a2v[n0 + i*16 + g*4 + r];
  #pragma unroll
  for (int j = 0; j < 4; ++j) b2r[j] = b2v[wv*64 + j*16 + lr];

  float rmax[4][4];
  #pragma unroll
  for (int i = 0; i < 4; ++i)
    #pragma unroll
    for (int r = 0; r < 4; ++r) rmax[i][r] = -3.4e38f;

  #pragma unroll
  for (int i = 0; i < 4; ++i)
    #pragma unroll
    for (int j = 0; j < 4; ++j)
      #pragma unroll
      for (int r = 0; r < 4; ++r){
        float d2 = fmaxf(a2r[i][r] + b2r[j] - 2.f*acc[i][j][r], 1e-12f);
        float lg = -temp * sqrtf(d2);
        acc[i][j][r] = lg;
        rmax[i][r] = fmaxf(rmax[i][r], lg);
      }
  #pragma unroll
  for (int i = 0; i < 4; ++i)
    #pragma unroll
    for (int r = 0; r < 4; ++r){
      float v = rmax[i][r];
      v = fmaxf(v, __shfl_xor(v, 1));
      v = fmaxf(v, __shfl_xor(v, 2));
      v = fmaxf(v, __shfl_xor(v, 4));
      v = fmaxf(v, __shfl_xor(v, 8));
      rmax[i][r] = v;
    }
  __syncthreads();
  if (lr == 0){
    #pragma unroll
    for (int i = 0; i < 4; ++i)
      #pragma unroll
      for (int r = 0; r < 4; ++r) red[wv*64 + i*16 + g*4 + r] = rmax[i][r];
  }
  __syncthreads();
  #pragma unroll
  for (int i = 0; i < 4; ++i)
    #pragma unroll
    for (int r = 0; r < 4; ++r){
      const int row = i*16 + g*4 + r;
      rmax[i][r] = fmaxf(fmaxf(red[row], red[64+row]), fmaxf(red[128+row], red[192+row]));
    }
  float rsum[4][4];
  #pragma unroll
  for (int i = 0; i < 4; ++i)
    #pragma unroll
    for (int r = 0; r < 4; ++r) rsum[i][r] = 0.f;
  #pragma unroll
  for (int i = 0; i < 4; ++i)
    #pragma unroll
    for (int j = 0; j < 4; ++j)
      #pragma unroll
      for (int r = 0; r < 4; ++r){
        float pe = __expf(acc[i][j][r] - rmax[i][r]);
        acc[i][j][r] = pe;
        rsum[i][r] += pe;
      }
  #pragma unroll
  for (int i = 0; i < 4; ++i)
    #pragma unroll
    for (int r = 0; r < 4; ++r){
      float v = rsum[i][r];
      v += __shfl_xor(v, 1);
      v += __shfl_xor(v, 2);
      v += __shfl_xor(v, 4);
      v += __shfl_xor(v, 8);
      rsum[i][r] = v;
    }
  __syncthreads();
  if (lr == 0){
    #pragma unroll
    for (int i = 0; i < 4; ++i)
      #pragma unroll
      for (int r = 0; r < 4; ++r) red[wv*64 + i*16 + g*4 + r] = rsum[i][r];
  }
  __syncthreads();
  #pragma unroll
  for (int i = 0; i < 4; ++i)
    #pragma unroll
    for (int r = 0; r < 4; ++r){
      const int row = i*16 + g*4 + r;
      const float invr = 1.f / (red[row] + red[64+row] + red[128+row] + red[192+row]);
      #pragma unroll
      for (int j = 0; j < 4; ++j)
        Sl[(size_t)row*264 + wv*64 + j*16 + lr] = f2bf(acc[i][j][r] * invr);
    }
  __syncthreads();                 // Sl visible; R2 free

  // ========== phase 2: T = Sl * Ct (no barriers, batch frag loads) ==========
  f32x4 acc2[4][9];
  #pragma unroll
  for (int i = 0; i < 4; ++i)
    #pragma unroll
    for (int j = 0; j < 9; ++j) acc2[i][j] = (f32x4){0.f,0.f,0.f,0.f};

  for (int mc = 0; mc < 8; ++mc){
    bf16x8 af2[4], bb2[9];
    #pragma unroll
    for (int i = 0; i < 4; ++i)
      af2[i] = *(const bf16x8*)&Sl[(size_t)(i*16 + lr)*264 + mc*32 + g*8];
    #pragma unroll
    for (int j = 0; j < 9; ++j)
      bb2[j] = *(const bf16x8*)(CtP + (((size_t)(wv*9 + j)*8 + mc)*64 + lane)*8);
    #pragma unroll
    for (int j = 0; j < 9; ++j)
      #pragma unroll
      for (int i = 0; i < 4; ++i)
        acc2[i][j] = __builtin_amdgcn_mfma_f32_16x16x32_bf16(af2[i], bb2[j], acc2[i][j], 0, 0, 0);
  }

  // ---- F write: two 288-p halves, skip-RMW coalesced ----------------------
  const float inv = 1.f / (temp + 1.f);
  const float tscale = temp * inv;
  #pragma unroll
  for (int h = 0; h < 2; ++h){
    __syncthreads();
    if ((wv >> 1) == h){
      const int pbase = (wv & 1) * 144;
      #pragma unroll
      for (int i = 0; i < 4; ++i)
        #pragma unroll
        for (int j = 0; j < 9; ++j)
          #pragma unroll
          for (int r = 0; r < 4; ++r)
            Fl[(i*16 + g*4 + r)*296 + pbase + j*16 + lr] = f2bf(acc2[i][j][r] * tscale);
    }
    __syncthreads();
    #pragma unroll
    for (int e = 0; e < 9; ++e){
      const int v = t + e*256;
      const int row = v / 36, col = (v - row*36) * 8;
      u16x8 tv = *(const u16x8*)&Fl[row*296 + col];
      u16x8 av;
      if constexpr (USE_AP){
        const int p0 = h*288 + col;
        const int kk = p0 >> 5, gg = (p0 >> 3) & 3;
        const int ii = row >> 4, lrr = row & 15;
        av = *(const u16x8*)(APb + ((size_t)((kk*4 + ii)*64 + gg*16 + lrr))*8);
      } else {
        av = *(const u16x8*)(Fout + (size_t)(n0 + row)*P_ + h*288 + col);
      }
      u16x8 o;
      #pragma unroll
      for (int e2 = 0; e2 < 8; ++e2)
        o[e2] = f2bf(bits2f(tv[e2]) + bits2f(av[e2]) * inv);
      *(u16x8*)(Fout + (size_t)(n0 + row)*P_ + h*288 + col) = o;
    }
  }
}

// ---- K4: MFMA GEMM out = WbP * F (+bias), mask fused into F staging --------
__global__ __launch_bounds__(256) void k4_conv(const u16* __restrict__ F,
    const u16* __restrict__ WbP, const float* __restrict__ bias,
    float* __restrict__ out){
  __shared__ short Fl[128*40];
  const int t = threadIdx.x;
  const int lane = t & 63;
  const int w = t >> 6;
  const int wn = w >> 1;
  const int ws = w & 1;
  const int g  = lane >> 4;
  const int lr = lane & 15;
  const int b  = blockIdx.y;
  const int s0 = blockIdx.x * 128;
  const u16* Fb = F + (size_t)b * ((size_t)P_ * L_);

  f32x4 acc[4][4];
  #pragma unroll
  for (int i = 0; i < 4; ++i)
    #pragma unroll
    for (int j = 0; j < 4; ++j) acc[i][j] = (f32x4){0.f,0.f,0.f,0.f};

  for (int step = 0; step < 18; ++step){
    const int q0 = step * 32;
    __syncthreads();
    #pragma unroll
    for (int e = 0; e < 2; ++e){
      const int c = t + e*256;
      const int ql = c & 31, sch = c >> 5;
      const int q  = q0 + ql;
      const int sbase = s0 + sch*8;
      const int scl = (sbase < L_ - 8) ? sbase : (L_ - 8);
      u16x8 v = *(const u16x8*)(Fb + (size_t)q*L_ + scl);
      const int q3 = q/3;
      const bool kx0 = (q - q3*3) == 0;
      const bool ky0 = (q3 % 3) == 0;
      const int r0 = sbase % 56;
      #pragma unroll
      for (int u = 0; u < 8; ++u){
        const bool m0 = ky0 && (sbase + u) < 56;
        const bool m1 = kx0 && ((r0 + u) == 0 || (r0 + u) == 56);
        Fl[(sch*8 + u)*40 + ql] = (m0 || m1) ? (short)0 : (short)v[u];
      }
    }
    __syncthreads();
    bf16x8 af[4], bb[4];
    #pragma unroll
    for (int i = 0; i < 4; ++i)
      af[i] = *(const bf16x8*)(WbP + (((size_t)(wn*4 + i)*18 + step)*64 + lane)*8);
    #pragma unroll
    for (int j = 0; j < 4; ++j)
      bb[j] = *(const bf16x8*)&Fl[(ws*64 + j*16 + lr)*40 + g*8];
    #pragma unroll
    for (int i = 0; i < 4; ++i)
      #pragma unroll
      for (int j = 0; j < 4; ++j)
        acc[i][j] = __builtin_amdgcn_mfma_f32_16x16x32_bf16(af[i], bb[j], acc[i][j], 0, 0, 0);
  }

  #pragma unroll
  for (int i = 0; i < 4; ++i)
    #pragma unroll
    for (int r = 0; r < 4; ++r){
      const int co = wn*64 + i*16 + g*4 + r;
      const float bv = bias[co];
      #pragma unroll
      for (int j = 0; j < 4; ++j){
        const int s = s0 + ws*64 + j*16 + lr;
        if (s < L_) out[((size_t)b*COUT + co)*L_ + s] = acc[i][j][r] + bv;
      }
    }
}

extern "C" void kernel_launch(void* const* d_in, const int* in_sizes, int n_in,
                              void* d_out, int out_size, void* d_ws, size_t ws_size,
                              hipStream_t stream){
  const float* x      = (const float*)d_in[0];
  const float* weight = (const float*)d_in[1];
  const float* bias   = (const float*)d_in[2];
  const float* cc     = (const float*)d_in[3];
  const float* temp_p = (const float*)d_in[4];
  float* out = (float*)d_out;

  char* ws = (char*)d_ws;
  const size_t NEED_AP = 232350720ULL;

  if (ws_size >= NEED_AP){
    u16*   AP  = (u16*)(ws);                 // 115,605,504 B (frag-major A)
    u16*   F   = (u16*)(ws + 115605504);     // 115,605,504 B (standard F)
    float* a2v = (float*)(ws + 231211008);   //     401,408 B
    float* b2v = (float*)(ws + 231612416);   //       1,024 B
    u16*   CbP = (u16*)(ws + 231613440);     //     294,912 B
    u16*   CtP = (u16*)(ws + 231908352);     //     294,912 B
    u16*   WbP = (u16*)(ws + 232203264);     //     147,456 B

    k0_prep       <<<436,          256, 0, stream>>>(cc, weight, CbP, CtP, b2v, WbP);
    k1b_unfold_ap <<<N_/64,        256, 0, stream>>>(x, AP, a2v);
    k23_fused<1>  <<<N_/64,        256, 0, stream>>>(AP, CbP, CtP, a2v, b2v, temp_p, F);
    k4_conv       <<<dim3(25, B_), 256, 0, stream>>>(F, WbP, bias, out);
  } else {
    u16*   A   = (u16*)(ws);                 // 115,605,504 B (standard A / F in place)
    float* a2v = (float*)(ws + 166985728);
    float* b2v = (float*)(ws + 167387136);
    u16*   CbP = (u16*)(ws + 167388160);
    u16*   CtP = (u16*)(ws + 167683072);
    u16*   WbP = (u16*)(ws + 167977984);

    k0_prep     <<<436,          256, 0, stream>>>(cc, weight, CbP, CtP, b2v, WbP);
    k1_unfold   <<<B_*HW,        256, 0, stream>>>(x, A, a2v);
    k23_fused<0><<<N_/64,        256, 0, stream>>>(A, CbP, CtP, a2v, b2v, temp_p, A);
    k4_conv     <<<dim3(25, B_), 256, 0, stream>>>(A, WbP, bias, out);
  }
}

// Round 12
// 294.422 us; speedup vs baseline: 1.2867x; 1.0256x over previous
//
#include <hip/hip_runtime.h>
#include <hip/hip_bf16.h>

#define B_    32
#define CIN   64
#define HW    56
#define COUT  128
#define M_    256
#define P_    576
#define L_    3136
#define N_    100352

typedef __hip_bfloat16 bf16;
typedef unsigned short u16;
typedef __attribute__((ext_vector_type(8))) short bf16x8;
typedef __attribute__((ext_vector_type(8))) unsigned short u16x8;
typedef __attribute__((ext_vector_type(4))) float f32x4;

__device__ __forceinline__ float bits2f(u16 u){ return __uint_as_float(((unsigned)u) << 16); }
__device__ __forceinline__ u16 f2bf(float f){
  bf16 h = __float2bfloat16(f);
  return *(u16*)&h;
}

// ---- K0: fragment-major operand layouts + b2 -------------------------------
// CbP[((wv*4+j)*18+k)*64 + lane] (16B) = Cb[m=wv*64+j*16+lr][p=k*32+g*8 ..+8]
// CtP[((q*9+j)*8+mc)*64 + lane]       = Ct[p=q*144+j*16+lr][m=mc*32+g*8 ..+8]
// WbP[((wn*4+i)*18+k)*64 + lane]      = Wb[co=wn*64+i*16+lr][q=k*32+g*8 ..+8]
__global__ __launch_bounds__(256) void k0_prep(const float* __restrict__ C,
                                               const float* __restrict__ W,
                                               u16* __restrict__ CbP, u16* __restrict__ CtP,
                                               float* __restrict__ b2v, u16* __restrict__ WbP){
  __shared__ float red[4];
  const int t = threadIdx.x;
  const int bid = blockIdx.x;
  if (bid < M_){
    const int m = bid;
    float s = 0.f;
    for (int p = t; p < P_; p += 256){
      float vr = bits2f(f2bf(C[(size_t)m*P_ + p]));
      s += vr*vr;
    }
    #pragma unroll
    for (int off = 32; off >= 1; off >>= 1) s += __shfl_xor(s, off);
    if ((t & 63) == 0) red[t >> 6] = s;
    __syncthreads();
    if (t == 0) b2v[m] = red[0] + red[1] + red[2] + red[3];
  } else if (bid < M_ + 72){
    const int u = (bid - M_)*256 + t;
    const int f = u >> 6, lane = u & 63;
    const int g = lane >> 4, lr = lane & 15;
    const int k = f % 18, fj = f / 18;
    const int j = fj & 3, wvq = fj >> 2;
    const int m = wvq*64 + j*16 + lr;
    const int p = k*32 + g*8;
    u16x8 o;
    #pragma unroll
    for (int c = 0; c < 8; ++c) o[c] = f2bf(C[(size_t)m*P_ + p + c]);
    *(u16x8*)&CbP[(size_t)u*8] = o;
  } else if (bid < M_ + 144){
    const int u = (bid - M_ - 72)*256 + t;
    const int f = u >> 6, lane = u & 63;
    const int g = lane >> 4, lr = lane & 15;
    const int mc = f & 7, fj = f >> 3;
    const int j = fj % 9, q = fj / 9;
    const int p = q*144 + j*16 + lr;
    const int m = mc*32 + g*8;
    u16x8 o;
    #pragma unroll
    for (int c = 0; c < 8; ++c) o[c] = f2bf(C[(size_t)(m + c)*P_ + p]);
    *(u16x8*)&CtP[(size_t)u*8] = o;
  } else {
    const int u = (bid - M_ - 144)*256 + t;
    const int f = u >> 6, lane = u & 63;
    const int g = lane >> 4, lr = lane & 15;
    const int k = f % 18, fi = f / 18;
    const int i = fi & 3, wn = fi >> 2;
    const int co = wn*64 + i*16 + lr;
    const int q = k*32 + g*8;
    u16x8 o;
    #pragma unroll
    for (int c = 0; c < 8; ++c) o[c] = f2bf(W[(size_t)co*P_ + q + c]);
    *(u16x8*)&WbP[(size_t)u*8] = o;
  }
}

// ---- K123: fused unfold + assign + transform. Block = 64 rows n. -----------
//  Stage x window (bf16) -> xt. P1: af produced per K-step into a 4-slot LDS
//  ring (div-free gather from xt), bb direct-from-L2 frags; 1 barrier/step,
//  no vmcnt. Softmax -> Sl. P2: T = Sl*CtP (no barriers). F-write: skip term
//  re-gathered from xt; F (standard [n][p]) to global for k4.
__global__ __launch_bounds__(256, 2) void k123(const float* __restrict__ x,
    const u16* __restrict__ CbP, const u16* __restrict__ CtP,
    const float* __restrict__ b2v, const float* __restrict__ temp_p,
    u16* __restrict__ F){
  __shared__ __align__(16) char lds[71680];
  u16*   xt  = (u16*)lds;                 // 64 x 264 u16 = 33792 B (persistent)
  char*  Bz  = lds + 33792;               // 37888 B overlay region
  u16*   ring= (u16*)Bz;                  // 4 slots x 2048 u16 = 16384 B (P1)
  u16*   Sl  = (u16*)Bz;                  // 64 x 264 u16 = 33792 B (softmax->P2)
  u16*   Fl  = (u16*)Bz;                  // 64 x 296 u16 = 37888 B (F staging)
  float* a2l = (float*)(lds + 67584);     // 64 f  (row norms)
  float* red = (float*)(lds + 67840);     // 256 f (softmax reduce)

  const int t = threadIdx.x;
  const int lane = t & 63;
  const int wv = t >> 6;
  const int g  = lane >> 4;
  const int lr = lane & 15;
  const int blk = blockIdx.x;
  const int n0 = blk * 64;
  const int b  = n0 / L_;
  const int l0 = n0 - b * L_;
  const int h0 = l0 / 56;
  const float temp = *temp_p;

  // ---- stage x window as bf16 ----
  const float* xb = x + (size_t)b * CIN * L_;
  {
    const int wc = t & 63;
    const int ix = wc - 1;
    #pragma unroll 4
    for (int iter = 0; iter < 64; ++iter){
      const int cw = (t >> 6) + iter*4;
      const int c  = cw & 63;
      const int ry = cw >> 6;
      const int iy = h0 - 1 + ry;
      float v = 0.f;
      if ((unsigned)iy < 56u && (unsigned)ix < 56u)
        v = xb[(size_t)c*L_ + iy*56 + ix];
      xt[c*264 + ry*64 + wc] = f2bf(v);
    }
  }
  __syncthreads();

  // ---- gather state (div-free walk; unit = (k*4+wv)*64+lane) ----
  const int l = l0 + wv*16 + lr;
  const int h = l / 56, w = l - h*56;
  const int hbw = (h - h0)*64 + w;
  const int p0g = g*8;
  int rr  = p0g - ((p0g >= 9) + (p0g >= 18))*9;
  int chB = ((p0g >= 9) + (p0g >= 18))*264;
  float s2 = 0.f;

  auto PRODUCE = [&](int e){
    const int di = (rr >= 3) + (rr >= 6);
    int dj = rr - di*3;
    int addr = chB + hbw + di*64 + dj;
    int rr2 = rr;
    u16x8 o;
    #pragma unroll
    for (int c2 = 0; c2 < 8; ++c2){
      const u16 val = xt[addr];
      o[c2] = val;
      const float vr = bits2f(val);
      s2 = fmaf(vr, vr, s2);
      const bool w9 = (rr2 == 8);
      const bool w3 = (dj == 2);
      addr += w9 ? 134 : (w3 ? 62 : 1);
      dj   = w3 ? 0 : dj + 1;
      rr2  = w9 ? 0 : rr2 + 1;
    }
    *(u16x8*)&ring[(e & 3)*2048 + (wv*64 + lane)*8] = o;
    const bool uw = (rr + 5 >= 9);
    rr  = rr + 5 - (uw ? 9 : 0);
    chB += uw ? 1056 : 792;
  };

  // ================= phase 1: G = A * Cb^T =================
  f32x4 acc[4][4];
  #pragma unroll
  for (int i = 0; i < 4; ++i)
    #pragma unroll
    for (int j = 0; j < 4; ++j) acc[i][j] = (f32x4){0.f,0.f,0.f,0.f};

  PRODUCE(0); PRODUCE(1); PRODUCE(2);
  bf16x8 bbc[4], bbn[4];
  #pragma unroll
  for (int j = 0; j < 4; ++j)
    bbc[j] = *(const bf16x8*)(CbP + (((size_t)(wv*4 + j)*18 + 0)*64 + lane)*8);

  #pragma unroll
  for (int k = 0; k < 18; ++k){
    __syncthreads();
    if (k + 3 < 18) PRODUCE(k + 3);
    bf16x8 af[4];
    #pragma unroll
    for (int i = 0; i < 4; ++i)
      af[i] = *(const bf16x8*)&ring[(k & 3)*2048 + (i*64 + lane)*8];
    if (k + 1 < 18){
      #pragma unroll
      for (int j = 0; j < 4; ++j)
        bbn[j] = *(const bf16x8*)(CbP + (((size_t)(wv*4 + j)*18 + (k+1))*64 + lane)*8);
    }
    #pragma unroll
    for (int i = 0; i < 4; ++i)
      #pragma unroll
      for (int j = 0; j < 4; ++j)
        acc[i][j] = __builtin_amdgcn_mfma_f32_16x16x32_bf16(af[i], bbc[j], acc[i][j], 0, 0, 0);
    if (k + 1 < 18){
      #pragma unroll
      for (int j = 0; j < 4; ++j) bbc[j] = bbn[j];
    }
  }

  // ---- a2 exchange ----
  s2 += __shfl_xor(s2, 16);
  s2 += __shfl_xor(s2, 32);
  if (g == 0) a2l[wv*16 + lr] = s2;
  __syncthreads();               // a2l visible; ring reads done

  // ---- softmax over all 256 m ----
  float a2r[4][4], b2r[4];
  #pragma unroll
  for (int i = 0; i < 4; ++i)
    #pragma unroll
    for (int r = 0; r < 4; ++r) a2r[i][r] = a2l[i*16 + g*4 + r];
  #pragma unroll
  for (int j = 0; j < 4; ++j) b2r[j] = b2v[wv*64 + j*16 + lr];

  float rmax[4][4];
  #pragma unroll
  for (int i = 0; i < 4; ++i)
    #pragma unroll
    for (int r = 0; r < 4; ++r) rmax[i][r] = -3.4e38f;

  #pragma unroll
  for (int i = 0; i < 4; ++i)
    #pragma unroll
    for (int j = 0; j < 4; ++j)
      #pragma unroll
      for (int r = 0; r < 4; ++r){
        float d2 = fmaxf(a2r[i][r] + b2r[j] - 2.f*acc[i][j][r], 1e-12f);
        float lg = -temp * sqrtf(d2);
        acc[i][j][r] = lg;
        rmax[i][r] = fmaxf(rmax[i][r], lg);
      }
  #pragma unroll
  for (int i = 0; i < 4; ++i)
    #pragma unroll
    for (int r = 0; r < 4; ++r){
      float v = rmax[i][r];
      v = fmaxf(v, __shfl_xor(v, 1));
      v = fmaxf(v, __shfl_xor(v, 2));
      v = fmaxf(v, __shfl_xor(v, 4));
      v = fmaxf(v, __shfl_xor(v, 8));
      rmax[i][r] = v;
    }
  __syncthreads();
  if (lr == 0){
    #pragma unroll
    for (int i = 0; i < 4; ++i)
      #pragma unroll
      for (int r = 0; r < 4; ++r) red[wv*64 + i*16 + g*4 + r] = rmax[i][r];
  }
  __syncthreads();
  #pragma unroll
  for (int i = 0; i < 4; ++i)
    #pragma unroll
    for (int r = 0; r < 4; ++r){
      const int row = i*16 + g*4 + r;
      rmax[i][r] = fmaxf(fmaxf(red[row], red[64+row]), fmaxf(red[128+row], red[192+row]));
    }
  float rsum[4][4];
  #pragma unroll
  for (int i = 0; i < 4; ++i)
    #pragma unroll
    for (int r = 0; r < 4; ++r) rsum[i][r] = 0.f;
  #pragma unroll
  for (int i = 0; i < 4; ++i)
    #pragma unroll
    for (int j = 0; j < 4; ++j)
      #pragma unroll
      for (int r = 0; r < 4; ++r){
        float pe = __expf(acc[i][j][r] - rmax[i][r]);
        acc[i][j][r] = pe;
        rsum[i][r] += pe;
      }
  #pragma unroll
  for (int i = 0; i < 4; ++i)
    #pragma unroll
    for (int r = 0; r < 4; ++r){
      float v = rsum[i][r];
      v += __shfl_xor(v, 1);
      v += __shfl_xor(v, 2);
      v += __shfl_xor(v, 4);
      v += __shfl_xor(v, 8);
      rsum[i][r] = v;
    }
  __syncthreads();
  if (lr == 0){
    #pragma unroll
    for (int i = 0; i < 4; ++i)
      #pragma unroll
      for (int r = 0; r < 4; ++r) red[wv*64 + i*16 + g*4 + r] = rsum[i][r];
  }
  __syncthreads();
  #pragma unroll
  for (int i = 0; i < 4; ++i)
    #pragma unroll
    for (int r = 0; r < 4; ++r){
      const int row = i*16 + g*4 + r;
      const float invr = 1.f / (red[row] + red[64+row] + red[128+row] + red[192+row]);
      #pragma unroll
      for (int j = 0; j < 4; ++j)
        Sl[(size_t)row*264 + wv*64 + j*16 + lr] = f2bf(acc[i][j][r] * invr);
    }
  __syncthreads();                 // Sl visible (ring dead)

  // ========== phase 2: T = Sl * Ct (no barriers, batch frag loads) ==========
  f32x4 acc2[4][9];
  #pragma unroll
  for (int i = 0; i < 4; ++i)
    #pragma unroll
    for (int j = 0; j < 9; ++j) acc2[i][j] = (f32x4){0.f,0.f,0.f,0.f};

  for (int mc = 0; mc < 8; ++mc){
    bf16x8 af2[4], bb2[9];
    #pragma unroll
    for (int i = 0; i < 4; ++i)
      af2[i] = *(const bf16x8*)&Sl[(size_t)(i*16 + lr)*264 + mc*32 + g*8];
    #pragma unroll
    for (int j = 0; j < 9; ++j)
      bb2[j] = *(const bf16x8*)(CtP + (((size_t)(wv*9 + j)*8 + mc)*64 + lane)*8);
    #pragma unroll
    for (int j = 0; j < 9; ++j)
      #pragma unroll
      for (int i = 0; i < 4; ++i)
        acc2[i][j] = __builtin_amdgcn_mfma_f32_16x16x32_bf16(af2[i], bb2[j], acc2[i][j], 0, 0, 0);
  }

  // ---- F write: two 288-p halves; skip term re-gathered from xt -----------
  const float inv = 1.f / (temp + 1.f);
  const float tscale = temp * inv;
  #pragma unroll
  for (int hh = 0; hh < 2; ++hh){
    __syncthreads();               // Fl region free (Sl reads / prev phase done)
    if ((wv >> 1) == hh){
      const int pbase = (wv & 1) * 144;
      #pragma unroll
      for (int i = 0; i < 4; ++i)
        #pragma unroll
        for (int j = 0; j < 9; ++j)
          #pragma unroll
          for (int r = 0; r < 4; ++r)
            Fl[(i*16 + g*4 + r)*296 + pbase + j*16 + lr] = f2bf(acc2[i][j][r] * tscale);
    }
    __syncthreads();
    #pragma unroll
    for (int e = 0; e < 9; ++e){
      const int v = t + e*256;
      const int row = v / 36, col = (v - row*36) * 8;
      u16x8 tv = *(const u16x8*)&Fl[row*296 + col];
      // re-gather A values from xt
      const int p0 = hh*288 + col;
      const int ch2 = p0 / 9;
      int rr2 = p0 - ch2*9;
      const int l2 = l0 + row;
      const int h2 = l2 / 56, w2 = l2 - h2*56;
      const int di2 = (rr2 >= 3) + (rr2 >= 6);
      int dj2 = rr2 - di2*3;
      int addr2 = ch2*264 + (h2 - h0 + di2)*64 + w2 + dj2;
      u16x8 o;
      #pragma unroll
      for (int c2 = 0; c2 < 8; ++c2){
        const u16 av_ = xt[addr2];
        o[c2] = f2bf(bits2f(tv[c2]) + bits2f(av_) * inv);
        const bool w9 = (rr2 == 8);
        const bool w3 = (dj2 == 2);
        addr2 += w9 ? 134 : (w3 ? 62 : 1);
        dj2 = w3 ? 0 : dj2 + 1;
        rr2 = w9 ? 0 : rr2 + 1;
      }
      *(u16x8*)(F + (size_t)(n0 + row)*P_ + hh*288 + col) = o;
    }
  }
}

// ---- K4: MFMA GEMM out = WbP * F (+bias), mask fused into F staging --------
// F viewed as [b][q][s] flat; B-tile transposed to [s][q] in LDS (stride 40).
__global__ __launch_bounds__(256) void k4_conv(const u16* __restrict__ F,
    const u16* __restrict__ WbP, const float* __restrict__ bias,
    float* __restrict__ out){
  __shared__ short Fl[128*40];
  const int t = threadIdx.x;
  const int lane = t & 63;
  const int w = t >> 6;
  const int wn = w >> 1;
  const int ws = w & 1;
  const int g  = lane >> 4;
  const int lr = lane & 15;
  const int b  = blockIdx.y;
  const int s0 = blockIdx.x * 128;
  const u16* Fb = F + (size_t)b * ((size_t)P_ * L_);

  f32x4 acc[4][4];
  #pragma unroll
  for (int i = 0; i < 4; ++i)
    #pragma unroll
    for (int j = 0; j < 4; ++j) acc[i][j] = (f32x4){0.f,0.f,0.f,0.f};

  for (int step = 0; step < 18; ++step){
    const int q0 = step * 32;
    __syncthreads();
    #pragma unroll
    for (int e = 0; e < 2; ++e){
      const int c = t + e*256;
      const int ql = c & 31, sch = c >> 5;
      const int q  = q0 + ql;
      const int sbase = s0 + sch*8;
      const int scl = (sbase < L_ - 8) ? sbase : (L_ - 8);
      u16x8 v = *(const u16x8*)(Fb + (size_t)q*L_ + scl);
      const int q3 = q/3;
      const bool kx0 = (q - q3*3) == 0;
      const bool ky0 = (q3 % 3) == 0;
      const int r0 = sbase % 56;
      #pragma unroll
      for (int u = 0; u < 8; ++u){
        const bool m0 = ky0 && (sbase + u) < 56;
        const bool m1 = kx0 && ((r0 + u) == 0 || (r0 + u) == 56);
        Fl[(sch*8 + u)*40 + ql] = (m0 || m1) ? (short)0 : (short)v[u];
      }
    }
    __syncthreads();
    bf16x8 af[4], bb[4];
    #pragma unroll
    for (int i = 0; i < 4; ++i)
      af[i] = *(const bf16x8*)(WbP + (((size_t)(wn*4 + i)*18 + step)*64 + lane)*8);
    #pragma unroll
    for (int j = 0; j < 4; ++j)
      bb[j] = *(const bf16x8*)&Fl[(ws*64 + j*16 + lr)*40 + g*8];
    #pragma unroll
    for (int i = 0; i < 4; ++i)
      #pragma unroll
      for (int j = 0; j < 4; ++j)
        acc[i][j] = __builtin_amdgcn_mfma_f32_16x16x32_bf16(af[i], bb[j], acc[i][j], 0, 0, 0);
  }

  #pragma unroll
  for (int i = 0; i < 4; ++i)
    #pragma unroll
    for (int r = 0; r < 4; ++r){
      const int co = wn*64 + i*16 + g*4 + r;
      const float bv = bias[co];
      #pragma unroll
      for (int j = 0; j < 4; ++j){
        const int s = s0 + ws*64 + j*16 + lr;
        if (s < L_) out[((size_t)b*COUT + co)*L_ + s] = acc[i][j][r] + bv;
      }
    }
}

extern "C" void kernel_launch(void* const* d_in, const int* in_sizes, int n_in,
                              void* d_out, int out_size, void* d_ws, size_t ws_size,
                              hipStream_t stream){
  const float* x      = (const float*)d_in[0];
  const float* weight = (const float*)d_in[1];
  const float* bias   = (const float*)d_in[2];
  const float* cc     = (const float*)d_in[3];
  const float* temp_p = (const float*)d_in[4];
  float* out = (float*)d_out;

  char* ws = (char*)d_ws;
  u16*   F   = (u16*)(ws);                 // 115,605,504 B (standard [n][p])
  float* b2v = (float*)(ws + 115605504);   //       1,024 B
  u16*   CbP = (u16*)(ws + 115606528);     //     294,912 B
  u16*   CtP = (u16*)(ws + 115901440);     //     294,912 B
  u16*   WbP = (u16*)(ws + 116196352);     //     147,456 B

  k0_prep <<<436,          256, 0, stream>>>(cc, weight, CbP, CtP, b2v, WbP);
  k123    <<<N_/64,        256, 0, stream>>>(x, CbP, CtP, b2v, temp_p, F);
  k4_conv <<<dim3(25, B_), 256, 0, stream>>>(F, WbP, bias, out);
}